// Round 5
// baseline (443.039 us; speedup 1.0000x reference)
//
#include <hip/hip_runtime.h>
#include <hip/hip_cooperative_groups.h>

namespace cg = cooperative_groups;

// ---------------------------------------------------------------------------
// HiPPO-LegT via scalar-kernel convolution, single cooperative kernel:
//   pred[b][t] = fac_t * sum_{s<=t} k[t-s] x[b][s] + D x[b][t],  k[tau]=C A^tau B
// k factorized: k[64q+r] = (C A^r) . (A^{64q} B) = W[r] . V[q]
//   W: 4 chains x 16 steps (starts C, C*A^16, C*A^32, (C*A^16)*A^32)
//   V: 4 chains x 16 steps with A^256 (starts B, A^64 B, A^128 B, A^64(A^128 B))
// Conv as MFMA GEMM vs Toeplitz T (round-4 algorithm), as the last phase.
// Fallback (if cooperative launch unavailable): round-4 multi-kernel pipeline.
// ---------------------------------------------------------------------------

#define LENGTH 4096

// ws layout (float offsets)
#define WS_P2    0
#define WS_P4    65536
#define WS_P8    131072
#define WS_P16   196608
#define WS_P32   262144
#define WS_P64T  327680
#define WS_P128T 393216
#define WS_P256T 458752
#define WS_W     524288   // 64 x 256
#define WS_V     540672   // 64 x 256
#define WS_K     557056   // 4096
#define WS_XH    561152   // 1M shorts = 524288 floats
#define WS_XL    1085440
#define WS_AH    1609728  // 256*64*8 shorts = 65536 floats
#define WS_AL    1675264

typedef __attribute__((ext_vector_type(8))) short bf16x8;
typedef __attribute__((ext_vector_type(4))) float f32x4;
#define MFMA(a, b, c) __builtin_amdgcn_mfma_f32_16x16x32_bf16(a, b, c, 0, 0, 0)

__device__ inline unsigned short f2bf(float f) {
    unsigned int u = __float_as_uint(f);
    return (unsigned short)((u + 0x7FFFu + ((u >> 16) & 1u)) >> 16);
}
__device__ inline void split2(float f, short& h, short& l) {
    unsigned short hu = f2bf(f);
    float fh = __uint_as_float((unsigned int)hu << 16);
    h = (short)hu;
    l = (short)f2bf(f - fh);
}

// ---- shared helpers for the cooperative kernel ----

// Z(row) = S(row) * S  (256x256 square), 512 thr: j=t&255, p=t>>8 (k-split 2)
__device__ __forceinline__ void sq_step(const float* __restrict__ S,
                                        float* __restrict__ Dst,
                                        int row, int j, int p, float* redl,
                                        bool trans) {
    const float* xr = S + row * 256 + 128 * p;
    const float* yc = S + (128 * p) * 256 + j;
    float a0 = 0.f, a1 = 0.f, a2 = 0.f, a3 = 0.f;
#pragma unroll
    for (int l = 0; l < 128; l += 4) {
        a0 = fmaf(xr[l + 0], yc[(l + 0) * 256], a0);
        a1 = fmaf(xr[l + 1], yc[(l + 1) * 256], a1);
        a2 = fmaf(xr[l + 2], yc[(l + 2) * 256], a2);
        a3 = fmaf(xr[l + 3], yc[(l + 3) * 256], a3);
    }
    float s = (a0 + a1) + (a2 + a3);
    if (p) redl[j] = s;
    __syncthreads();
    if (!p) {
        float z = s + redl[j];
        if (trans) Dst[j * 256 + row] = z;
        else       Dst[row * 256 + j] = z;
    }
    __syncthreads();
}

// curl[j] = sum_i v[i] * M[i*256+j]   (row-vector x matrix)
__device__ __forceinline__ void rv_mm(const float* __restrict__ v,
                                      const float* __restrict__ M,
                                      float* curl, float* redl, int j, int p) {
    float s0 = 0.f, s1 = 0.f;
#pragma unroll
    for (int ii = 0; ii < 128; ii += 2) {
        s0 = fmaf(v[128 * p + ii],     M[(128 * p + ii) * 256 + j],     s0);
        s1 = fmaf(v[128 * p + ii + 1], M[(128 * p + ii + 1) * 256 + j], s1);
    }
    float s = s0 + s1;
    if (p) redl[j] = s;
    __syncthreads();
    if (!p) curl[j] = s + redl[j];
    __syncthreads();
}

// curl[i] = sum_j MT[j*256+i] * v[j]   (matrix(T-stored) x col-vector)
__device__ __forceinline__ void cv_mm(const float* __restrict__ MT,
                                      const float* __restrict__ v,
                                      float* curl, float* redl, int i, int p) {
    float s0 = 0.f, s1 = 0.f;
#pragma unroll
    for (int jj = 0; jj < 128; jj += 2) {
        s0 = fmaf(MT[(128 * p + jj) * 256 + i],     v[128 * p + jj],     s0);
        s1 = fmaf(MT[(128 * p + jj + 1) * 256 + i], v[128 * p + jj + 1], s1);
    }
    float s = s0 + s1;
    if (p) redl[i] = s;
    __syncthreads();
    if (!p) curl[i] = s + redl[i];
    __syncthreads();
}

// ---- convm fragment machinery (shared with fallback kernel) ----
struct Frag {
    bf16x8 bh0, bh1, bl0, bl1;
    bf16x8 ah0, ah1, ah2, ah3, al0, al1, al2, al3;
    int d0, tile;
};

#define LOADF(F, IDX_) do {                                                    \
        const int i_ = (IDX_);                                                 \
        const int tl_ = (i_ < nA) ? 0 : 1;                                     \
        const int cc_ = i_ - (tl_ ? nA : 0);                                   \
        const int xo_ = ((cc_ * 16 + bt2) * 64 + lane) * 8;                    \
        F.bh0 = *reinterpret_cast<const bf16x8*>(XH + xo_);                    \
        F.bh1 = *reinterpret_cast<const bf16x8*>(XH + xo_ + 512);              \
        F.bl0 = *reinterpret_cast<const bf16x8*>(XL + xo_);                    \
        F.bl1 = *reinterpret_cast<const bf16x8*>(XL + xo_ + 512);              \
        const int d_ = (tl_ ? tB64 : tA64) - cc_ * 32;                         \
        F.d0 = d_; F.tile = tl_;                                               \
        const int m0_ = (d_ > 0 ? d_ : 0) >> 4;                                \
        const int m1_ = (d_ + 16 > 0 ? d_ + 16 : 0) >> 4;                      \
        const int m2_ = (d_ + 32 > 0 ? d_ + 32 : 0) >> 4;                      \
        const int m3_ = (d_ + 48 > 0 ? d_ + 48 : 0) >> 4;                      \
        F.ah0 = *reinterpret_cast<const bf16x8*>(AH + (m0_ * 64 + lane) * 8);  \
        F.al0 = *reinterpret_cast<const bf16x8*>(AL + (m0_ * 64 + lane) * 8);  \
        F.ah1 = *reinterpret_cast<const bf16x8*>(AH + (m1_ * 64 + lane) * 8);  \
        F.al1 = *reinterpret_cast<const bf16x8*>(AL + (m1_ * 64 + lane) * 8);  \
        F.ah2 = *reinterpret_cast<const bf16x8*>(AH + (m2_ * 64 + lane) * 8);  \
        F.al2 = *reinterpret_cast<const bf16x8*>(AL + (m2_ * 64 + lane) * 8);  \
        F.ah3 = *reinterpret_cast<const bf16x8*>(AH + (m3_ * 64 + lane) * 8);  \
        F.al3 = *reinterpret_cast<const bf16x8*>(AL + (m3_ * 64 + lane) * 8);  \
    } while (0)

#define ONER(F, T, R, AHF, ALF)                                                \
        if (F.d0 + 16 * R >= 0) {                                              \
            acc[T][R][0] = MFMA(F.AHF, F.bh0, acc[T][R][0]);                   \
            acc[T][R][1] = MFMA(F.AHF, F.bh1, acc[T][R][1]);                   \
            acc[T][R][0] = MFMA(F.AHF, F.bl0, acc[T][R][0]);                   \
            acc[T][R][1] = MFMA(F.AHF, F.bl1, acc[T][R][1]);                   \
            acc[T][R][0] = MFMA(F.ALF, F.bh0, acc[T][R][0]);                   \
            acc[T][R][1] = MFMA(F.ALF, F.bh1, acc[T][R][1]);                   \
        }

#define APPLY(F) do {                                                          \
        if (F.tile == 0) {                                                     \
            ONER(F, 0, 0, ah0, al0) ONER(F, 0, 1, ah1, al1)                    \
            ONER(F, 0, 2, ah2, al2) ONER(F, 0, 3, ah3, al3)                    \
        } else {                                                               \
            ONER(F, 1, 0, ah0, al0) ONER(F, 1, 1, ah1, al1)                    \
            ONER(F, 1, 2, ah2, al2) ONER(F, 1, 3, ah3, al3)                    \
        }                                                                      \
    } while (0)

// ===========================================================================
// The single cooperative mega-kernel: 256 blocks x 512 threads (1 block/CU)
// ===========================================================================
__global__ __launch_bounds__(512) void megak(const float* __restrict__ x,
                                             const float* __restrict__ A,
                                             const float* __restrict__ B,
                                             const float* __restrict__ C,
                                             const float* __restrict__ Dp,
                                             float* __restrict__ out,
                                             float* __restrict__ ws) {
    cg::grid_group grid = cg::this_grid();
    const int bid = blockIdx.x;
    const int t = threadIdx.x;
    const int j = t & 255, p = t >> 8;

    __shared__ __align__(16) float lds[16 * 64 * 34];
    float* curl = lds;
    float* redl = lds + 256;

    float* P2    = ws + WS_P2;
    float* P4    = ws + WS_P4;
    float* P8    = ws + WS_P8;
    float* P16   = ws + WS_P16;
    float* P32   = ws + WS_P32;
    float* P64T  = ws + WS_P64T;
    float* P128T = ws + WS_P128T;
    float* P256T = ws + WS_P256T;
    float* Wm    = ws + WS_W;
    float* Vm    = ws + WS_V;
    float* K     = ws + WS_K;
    short* XH    = (short*)(ws + WS_XH);
    short* XL    = (short*)(ws + WS_XL);
    short* AH    = (short*)(ws + WS_AH);
    short* AL    = (short*)(ws + WS_AL);

    // ---- ph0: xsplit (1 job per wave) then P2 = A*A ----
    {
        const int w = t >> 6, lane = t & 63;
        const int pj = bid * 8 + w;            // 0..2047
        const int c = pj >> 4, blk = pj & 15;
        const int b = blk * 16 + (lane & 15);
        const int s0 = c * 32 + 8 * (lane >> 4);
        const float4 v0 = reinterpret_cast<const float4*>(&x[b * LENGTH + s0])[0];
        const float4 v1 = reinterpret_cast<const float4*>(&x[b * LENGTH + s0])[1];
        const float f[8] = {v0.x, v0.y, v0.z, v0.w, v1.x, v1.y, v1.z, v1.w};
        bf16x8 hv, lv;
#pragma unroll
        for (int e = 0; e < 8; ++e) {
            short h_, l_;
            split2(f[e], h_, l_);
            hv[e] = h_; lv[e] = l_;
        }
        const int off = (pj * 64 + lane) * 8;
        *reinterpret_cast<bf16x8*>(XH + off) = hv;
        *reinterpret_cast<bf16x8*>(XL + off) = lv;

        sq_step(A, P2, bid, j, p, redl, false);
    }
    grid.sync();
    // ---- ph1..ph4: squarings ----
    sq_step(P2, P4, bid, j, p, redl, false);
    grid.sync();
    sq_step(P4, P8, bid, j, p, redl, false);
    grid.sync();
    sq_step(P8, P16, bid, j, p, redl, false);
    grid.sync();
    sq_step(P16, P32, bid, j, p, redl, false);
    grid.sync();
    // ---- ph5: P64T (transposed store) ----
    sq_step(P32, P64T, bid, j, p, redl, true);
    grid.sync();
    // ---- ph6: P128T = P64T*P64T (blocks 4..255) || W chains (blocks 0..3) ----
    if (bid >= 4) {
        sq_step(P64T, P128T, bid - 4, j, p, redl, false);
        if (bid < 8) sq_step(P64T, P128T, 252 + (bid - 4), j, p, redl, false);
    } else {
        const int c = bid;
        float areg[128];
#pragma unroll
        for (int ii = 0; ii < 128; ++ii) areg[ii] = A[(128 * p + ii) * 256 + j];
        if (c == 0) {
            if (t < 256) curl[t] = C[t];
            __syncthreads();
        } else if (c == 1) {
            rv_mm(C, P16, curl, redl, j, p);
        } else if (c == 2) {
            rv_mm(C, P32, curl, redl, j, p);
        } else {
            rv_mm(C, P16, curl, redl, j, p);
            rv_mm(curl, P32, curl, redl, j, p);
        }
        for (int s_ = 0; s_ < 16; ++s_) {
            if (!p) Wm[(16 * c + s_) * 256 + j] = curl[j];
            if (s_ == 15) break;
            float s0 = 0.f, s1 = 0.f;
#pragma unroll
            for (int m = 0; m < 32; ++m) {
                float4 c4 = *reinterpret_cast<const float4*>(&curl[128 * p + 4 * m]);
                s0 = fmaf(c4.x, areg[4 * m + 0], s0);
                s1 = fmaf(c4.y, areg[4 * m + 1], s1);
                s0 = fmaf(c4.z, areg[4 * m + 2], s0);
                s1 = fmaf(c4.w, areg[4 * m + 3], s1);
            }
            float s = s0 + s1;
            if (p) redl[j] = s;
            __syncthreads();
            if (!p) curl[j] = s + redl[j];
            __syncthreads();
        }
    }
    grid.sync();
    // ---- ph7: P256T = P128T*P128T (blocks 4..255) || V starts (blocks 0..3) ----
    if (bid >= 4) {
        sq_step(P128T, P256T, bid - 4, j, p, redl, false);
        if (bid < 8) sq_step(P128T, P256T, 252 + (bid - 4), j, p, redl, false);
    } else {
        const int c = bid;
        if (c == 0) {
            if (t < 256) curl[t] = B[t];
            __syncthreads();
        } else if (c == 1) {
            cv_mm(P64T, B, curl, redl, j, p);
        } else if (c == 2) {
            cv_mm(P128T, B, curl, redl, j, p);
        } else {
            cv_mm(P128T, B, curl, redl, j, p);
            cv_mm(P64T, curl, curl, redl, j, p);
        }
    }
    grid.sync();
    // ---- ph8: V chains (blocks 0..3), step A^256 ----
    if (bid < 4) {
        const int c = bid, i = j;
        float mreg[128];
#pragma unroll
        for (int jj = 0; jj < 128; ++jj) mreg[jj] = P256T[(128 * p + jj) * 256 + i];
        for (int s_ = 0; s_ < 16; ++s_) {
            if (!p) Vm[(4 * s_ + c) * 256 + i] = curl[i];
            if (s_ == 15) break;
            float s0 = 0.f, s1 = 0.f;
#pragma unroll
            for (int m = 0; m < 32; ++m) {
                float4 c4 = *reinterpret_cast<const float4*>(&curl[128 * p + 4 * m]);
                s0 = fmaf(c4.x, mreg[4 * m + 0], s0);
                s1 = fmaf(c4.y, mreg[4 * m + 1], s1);
                s0 = fmaf(c4.z, mreg[4 * m + 2], s0);
                s1 = fmaf(c4.w, mreg[4 * m + 3], s1);
            }
            float s = s0 + s1;
            if (p) redl[i] = s;
            __syncthreads();
            if (!p) curl[i] = s + redl[i];
            __syncthreads();
        }
    }
    grid.sync();
    // ---- ph9: kdot: K[64q+r] = W[r].V[q] ----
    if (bid < 64) {
        const int r = t >> 3, h = t & 7;
        float s = 0.f;
#pragma unroll
        for (int m = 0; m < 32; ++m)
            s = fmaf(Wm[r * 256 + h * 32 + m], Vm[bid * 256 + h * 32 + m], s);
        s += __shfl_xor(s, 1, 64);
        s += __shfl_xor(s, 2, 64);
        s += __shfl_xor(s, 4, 64);
        if (h == 0) K[bid * 64 + r] = s;
    }
    grid.sync();
    // ---- ph10: afrag ----
    if (bid < 32) {
        const int w = t >> 6, lane = t & 63;
        const int m = bid * 8 + w;
        bf16x8 hv, lv;
#pragma unroll
        for (int e = 0; e < 8; ++e) {
            const int kidx = 16 * m + (lane & 15) - 8 * (lane >> 4) - e;
            const float kv = (kidx >= 0) ? K[kidx] : 0.f;
            short h_, l_;
            split2(kv, h_, l_);
            hv[e] = h_; lv[e] = l_;
        }
        const int off = (m * 64 + lane) * 8;
        *reinterpret_cast<bf16x8*>(AH + off) = hv;
        *reinterpret_cast<bf16x8*>(AL + off) = lv;
    }
    grid.sync();
    // ---- ph11: convm (round-4 algorithm) ----
    {
        const int pr = bid & 31;
        const int bt = bid >> 5;
        const int w = t >> 6, lane = t & 63;
        const int tA64 = pr * 64, tB64 = (63 - pr) * 64;
        const int nA = 2 * pr + 2;
        const int bt2 = bt * 2;

        f32x4 acc[2][4][2];
#pragma unroll
        for (int t_ = 0; t_ < 2; ++t_)
#pragma unroll
            for (int r_ = 0; r_ < 4; ++r_)
#pragma unroll
                for (int c_ = 0; c_ < 2; ++c_) acc[t_][r_][c_] = f32x4{0.f, 0.f, 0.f, 0.f};

        Frag f0, f1;
        LOADF(f0, w);
        int idx = w;
        while (true) {
            const int n1 = idx + 8;
            const bool h1 = n1 < 130;
            if (h1) LOADF(f1, n1);
            APPLY(f0);
            if (!h1) break;
            const int n2 = n1 + 8;
            const bool h2 = n2 < 130;
            if (h2) LOADF(f0, n2);
            APPLY(f1);
            if (!h2) break;
            idx = n2;
        }

        const int lq = lane >> 4, lr = lane & 15;
#pragma unroll
        for (int t_ = 0; t_ < 2; ++t_)
#pragma unroll
            for (int r_ = 0; r_ < 4; ++r_)
#pragma unroll
                for (int c_ = 0; c_ < 2; ++c_)
#pragma unroll
                    for (int e_ = 0; e_ < 4; ++e_)
                        lds[((w * 2 + t_) * 64 + (r_ * 16 + lq * 4 + e_)) * 34 +
                            (c_ * 16 + lr)] = acc[t_][r_][c_][e_];
        __syncthreads();

        const float D = Dp[0];
        const int b = t >> 4;
        const int t4 = (t & 15) * 4;
#pragma unroll
        for (int t_ = 0; t_ < 2; ++t_) {
            const int tbase = t_ ? tB64 : tA64;
            float s0 = 0.f, s1 = 0.f, s2 = 0.f, s3 = 0.f;
#pragma unroll
            for (int w_ = 0; w_ < 8; ++w_) {
                const float* lp = &lds[((w_ * 2 + t_) * 64 + t4) * 34 + b];
                s0 += lp[0]; s1 += lp[34]; s2 += lp[68]; s3 += lp[102];
            }
            const int g = (bt * 32 + b) * LENGTH + tbase + t4;
            const float4 xv = *reinterpret_cast<const float4*>(x + g);
            float4 o;
            o.x = 2.f * s0 + D * xv.x;
            o.y = 2.f * s1 + D * xv.y;
            o.z = 2.f * s2 + D * xv.z;
            o.w = 2.f * s3 + D * xv.w;
            if (tbase == 0 && t4 == 0) o.x -= s0;
            *reinterpret_cast<float4*>(out + g) = o;
        }
    }
}

// ===========================================================================
// Fallback pipeline (round-4), used only if cooperative launch fails.
// ===========================================================================
__global__ __launch_bounds__(1024) void mmrow(const float* __restrict__ X,
                                              const float* __restrict__ Y,
                                              float* __restrict__ Z) {
    const int i = blockIdx.x, t = threadIdx.x;
    const int j = t & 255, p = t >> 8;
    __shared__ float red[3][256];
    const float* xr = X + i * 256 + 64 * p;
    const float* yc = Y + (64 * p) * 256 + j;
    float a0 = 0.f, a1 = 0.f, a2 = 0.f, a3 = 0.f;
#pragma unroll
    for (int l = 0; l < 64; l += 4) {
        a0 = fmaf(xr[l + 0], yc[(l + 0) * 256], a0);
        a1 = fmaf(xr[l + 1], yc[(l + 1) * 256], a1);
        a2 = fmaf(xr[l + 2], yc[(l + 2) * 256], a2);
        a3 = fmaf(xr[l + 3], yc[(l + 3) * 256], a3);
    }
    float s = (a0 + a1) + (a2 + a3);
    if (p) red[p - 1][j] = s;
    __syncthreads();
    if (p == 0) Z[i * 256 + j] = s + red[0][j] + red[1][j] + red[2][j];
}

__global__ __launch_bounds__(1024) void mm2(const float* __restrict__ P32,
                                            float* __restrict__ P64T) {
    const int i = blockIdx.x, t = threadIdx.x;
    const int j = t & 255, p = t >> 8;
    __shared__ float red[3][256];
    const float* xr = P32 + i * 256 + 64 * p;
    const float* yc = P32 + (64 * p) * 256 + j;
    float a0 = 0.f, a1 = 0.f, a2 = 0.f, a3 = 0.f;
#pragma unroll
    for (int l = 0; l < 64; l += 4) {
        a0 = fmaf(xr[l + 0], yc[(l + 0) * 256], a0);
        a1 = fmaf(xr[l + 1], yc[(l + 1) * 256], a1);
        a2 = fmaf(xr[l + 2], yc[(l + 2) * 256], a2);
        a3 = fmaf(xr[l + 3], yc[(l + 3) * 256], a3);
    }
    float s = (a0 + a1) + (a2 + a3);
    if (p) red[p - 1][j] = s;
    __syncthreads();
    if (p == 0) P64T[j * 256 + i] = s + red[0][j] + red[1][j] + red[2][j];
}

__global__ __launch_bounds__(1024) void wvgen(const float* __restrict__ A,
                                              const float* __restrict__ B,
                                              const float* __restrict__ C,
                                              const float* __restrict__ P32,
                                              const float* __restrict__ P64T,
                                              const float* __restrict__ P128T,
                                              float* __restrict__ W,
                                              float* __restrict__ V) {
    const int t = threadIdx.x;
    const int bid = blockIdx.x;
    const int j = t & 255, p = t >> 8;
    __shared__ float cur[256];
    __shared__ float red[4][256];

    if (bid < 2) {
        float areg[64];
#pragma unroll
        for (int ii = 0; ii < 64; ++ii) areg[ii] = A[(64 * p + ii) * 256 + j];
        if (bid == 0) {
            if (t < 256) cur[t] = C[t];
            __syncthreads();
        } else {
            float s0 = 0.f, s1 = 0.f, s2 = 0.f, s3 = 0.f;
#pragma unroll 4
            for (int ii = 0; ii < 64; ii += 4) {
                s0 = fmaf(C[64 * p + ii + 0], P32[(64 * p + ii + 0) * 256 + j], s0);
                s1 = fmaf(C[64 * p + ii + 1], P32[(64 * p + ii + 1) * 256 + j], s1);
                s2 = fmaf(C[64 * p + ii + 2], P32[(64 * p + ii + 2) * 256 + j], s2);
                s3 = fmaf(C[64 * p + ii + 3], P32[(64 * p + ii + 3) * 256 + j], s3);
            }
            red[p][j] = (s0 + s1) + (s2 + s3);
            __syncthreads();
            if (p == 0) cur[j] = red[0][j] + red[1][j] + red[2][j] + red[3][j];
            __syncthreads();
        }
        const int base = bid * 32;
        if (p == 0) W[base * 256 + j] = cur[j];
        for (int r = 1; r < 32; ++r) {
            float s0 = 0.f, s1 = 0.f, s2 = 0.f, s3 = 0.f;
#pragma unroll
            for (int m = 0; m < 16; ++m) {
                float4 c4 = *reinterpret_cast<const float4*>(&cur[64 * p + 4 * m]);
                s0 = fmaf(c4.x, areg[4 * m + 0], s0);
                s1 = fmaf(c4.y, areg[4 * m + 1], s1);
                s2 = fmaf(c4.z, areg[4 * m + 2], s2);
                s3 = fmaf(c4.w, areg[4 * m + 3], s3);
            }
            red[p][j] = (s0 + s1) + (s2 + s3);
            __syncthreads();
            if (p == 0) {
                float s = red[0][j] + red[1][j] + red[2][j] + red[3][j];
                cur[j] = s;
                W[(base + r) * 256 + j] = s;
            }
            __syncthreads();
        }
    } else {
        const int i = j;
        float mreg[64];
#pragma unroll
        for (int jj = 0; jj < 64; ++jj) mreg[jj] = P128T[(64 * p + jj) * 256 + i];
        if (t < 256) cur[t] = B[t];
        __syncthreads();
        if (bid == 3) {
            float s0 = 0.f, s1 = 0.f, s2 = 0.f, s3 = 0.f;
#pragma unroll 4
            for (int jj = 0; jj < 64; jj += 4) {
                s0 = fmaf(P64T[(64 * p + jj + 0) * 256 + i], cur[64 * p + jj + 0], s0);
                s1 = fmaf(P64T[(64 * p + jj + 1) * 256 + i], cur[64 * p + jj + 1], s1);
                s2 = fmaf(P64T[(64 * p + jj + 2) * 256 + i], cur[64 * p + jj + 2], s2);
                s3 = fmaf(P64T[(64 * p + jj + 3) * 256 + i], cur[64 * p + jj + 3], s3);
            }
            red[p][i] = (s0 + s1) + (s2 + s3);
            __syncthreads();
            if (p == 0) cur[i] = red[0][i] + red[1][i] + red[2][i] + red[3][i];
            __syncthreads();
        }
        const int off = bid - 2;
        for (int m = 0; m < 32; ++m) {
            if (p == 0) V[(2 * m + off) * 256 + i] = cur[i];
            if (m == 31) break;
            float s0 = 0.f, s1 = 0.f, s2 = 0.f, s3 = 0.f;
#pragma unroll
            for (int mm = 0; mm < 16; ++mm) {
                float4 c4 = *reinterpret_cast<const float4*>(&cur[64 * p + 4 * mm]);
                s0 = fmaf(c4.x, mreg[4 * mm + 0], s0);
                s1 = fmaf(c4.y, mreg[4 * mm + 1], s1);
                s2 = fmaf(c4.z, mreg[4 * mm + 2], s2);
                s3 = fmaf(c4.w, mreg[4 * mm + 3], s3);
            }
            red[p][i] = (s0 + s1) + (s2 + s3);
            __syncthreads();
            if (p == 0) cur[i] = red[0][i] + red[1][i] + red[2][i] + red[3][i];
            __syncthreads();
        }
    }
}

__global__ __launch_bounds__(256) void kdot(const float* __restrict__ W,
                                            const float* __restrict__ V,
                                            float* __restrict__ K) {
    const int q = blockIdx.x, tid = threadIdx.x;
    const int r = tid & 63, p = tid >> 6;
    __shared__ float Wl[64 * 257];
    __shared__ float Vl[256];
    __shared__ float red[4][64];
    for (int u = 0; u < 64; ++u) Wl[u * 257 + tid] = W[u * 256 + tid];
    Vl[tid] = V[q * 256 + tid];
    __syncthreads();
    float s0 = 0.f, s1 = 0.f;
#pragma unroll
    for (int m = 0; m < 64; m += 2) {
        s0 = fmaf(Wl[r * 257 + 64 * p + m + 0], Vl[64 * p + m + 0], s0);
        s1 = fmaf(Wl[r * 257 + 64 * p + m + 1], Vl[64 * p + m + 1], s1);
    }
    red[p][r] = s0 + s1;
    __syncthreads();
    if (tid < 64) K[q * 64 + tid] = red[0][tid] + red[1][tid] + red[2][tid] + red[3][tid];
}

__global__ __launch_bounds__(256) void xsplit(const float* __restrict__ x,
                                              short* __restrict__ XH,
                                              short* __restrict__ XL) {
    const int w = threadIdx.x >> 6, lane = threadIdx.x & 63;
    const int p = blockIdx.x * 4 + w;
    const int c = p >> 4, blk = p & 15;
    const int b = blk * 16 + (lane & 15);
    const int s0 = c * 32 + 8 * (lane >> 4);
    const float4 v0 = reinterpret_cast<const float4*>(&x[b * LENGTH + s0])[0];
    const float4 v1 = reinterpret_cast<const float4*>(&x[b * LENGTH + s0])[1];
    const float f[8] = {v0.x, v0.y, v0.z, v0.w, v1.x, v1.y, v1.z, v1.w};
    bf16x8 hv, lv;
#pragma unroll
    for (int e = 0; e < 8; ++e) {
        short h, l;
        split2(f[e], h, l);
        hv[e] = h; lv[e] = l;
    }
    const int off = (p * 64 + lane) * 8;
    *reinterpret_cast<bf16x8*>(XH + off) = hv;
    *reinterpret_cast<bf16x8*>(XL + off) = lv;
}

__global__ __launch_bounds__(256) void afrag(const float* __restrict__ K,
                                             short* __restrict__ AH,
                                             short* __restrict__ AL) {
    const int m = blockIdx.x * 4 + (threadIdx.x >> 6);
    const int lane = threadIdx.x & 63;
    bf16x8 hv, lv;
#pragma unroll
    for (int e = 0; e < 8; ++e) {
        const int kidx = 16 * m + (lane & 15) - 8 * (lane >> 4) - e;
        const float kv = (kidx >= 0) ? K[kidx] : 0.f;
        short h, l;
        split2(kv, h, l);
        hv[e] = h; lv[e] = l;
    }
    const int off = (m * 64 + lane) * 8;
    *reinterpret_cast<bf16x8*>(AH + off) = hv;
    *reinterpret_cast<bf16x8*>(AL + off) = lv;
}

__global__ __launch_bounds__(512) void convm(const short* __restrict__ XH,
                                             const short* __restrict__ XL,
                                             const short* __restrict__ AH,
                                             const short* __restrict__ AL,
                                             const float* __restrict__ x,
                                             const float* __restrict__ Dp,
                                             float* __restrict__ out) {
    const int pr = blockIdx.x & 31;
    const int bt = blockIdx.x >> 5;
    const int tid = threadIdx.x;
    const int w = tid >> 6, lane = tid & 63;
    const int tA64 = pr * 64, tB64 = (63 - pr) * 64;
    const int nA = 2 * pr + 2;
    const int bt2 = bt * 2;

    __shared__ float lds[16 * 64 * 34];

    f32x4 acc[2][4][2];
#pragma unroll
    for (int t_ = 0; t_ < 2; ++t_)
#pragma unroll
        for (int r_ = 0; r_ < 4; ++r_)
#pragma unroll
            for (int c_ = 0; c_ < 2; ++c_) acc[t_][r_][c_] = f32x4{0.f, 0.f, 0.f, 0.f};

    Frag f0, f1;
    LOADF(f0, w);
    int idx = w;
    while (true) {
        const int n1 = idx + 8;
        const bool h1 = n1 < 130;
        if (h1) LOADF(f1, n1);
        APPLY(f0);
        if (!h1) break;
        const int n2 = n1 + 8;
        const bool h2 = n2 < 130;
        if (h2) LOADF(f0, n2);
        APPLY(f1);
        if (!h2) break;
        idx = n2;
    }

    const int lq = lane >> 4, lr = lane & 15;
#pragma unroll
    for (int t_ = 0; t_ < 2; ++t_)
#pragma unroll
        for (int r_ = 0; r_ < 4; ++r_)
#pragma unroll
            for (int c_ = 0; c_ < 2; ++c_)
#pragma unroll
                for (int e_ = 0; e_ < 4; ++e_)
                    lds[((w * 2 + t_) * 64 + (r_ * 16 + lq * 4 + e_)) * 34 +
                        (c_ * 16 + lr)] = acc[t_][r_][c_][e_];
    __syncthreads();

    const float D = Dp[0];
    const int b = tid >> 4;
    const int t4 = (tid & 15) * 4;
#pragma unroll
    for (int t_ = 0; t_ < 2; ++t_) {
        const int tbase = t_ ? tB64 : tA64;
        float s0 = 0.f, s1 = 0.f, s2 = 0.f, s3 = 0.f;
#pragma unroll
        for (int w_ = 0; w_ < 8; ++w_) {
            const float* lp = &lds[((w_ * 2 + t_) * 64 + t4) * 34 + b];
            s0 += lp[0]; s1 += lp[34]; s2 += lp[68]; s3 += lp[102];
        }
        const int g = (bt * 32 + b) * LENGTH + tbase + t4;
        const float4 xv = *reinterpret_cast<const float4*>(x + g);
        float4 o;
        o.x = 2.f * s0 + D * xv.x;
        o.y = 2.f * s1 + D * xv.y;
        o.z = 2.f * s2 + D * xv.z;
        o.w = 2.f * s3 + D * xv.w;
        if (tbase == 0 && t4 == 0) o.x -= s0;
        *reinterpret_cast<float4*>(out + g) = o;
    }
}

extern "C" void kernel_launch(void* const* d_in, const int* in_sizes, int n_in,
                              void* d_out, int out_size, void* d_ws, size_t ws_size,
                              hipStream_t stream) {
    const float* x  = (const float*)d_in[0];
    const float* A  = (const float*)d_in[1];
    const float* B  = (const float*)d_in[2];
    const float* C  = (const float*)d_in[3];
    const float* Dp = (const float*)d_in[4];
    float* out = (float*)d_out;
    float* ws  = (float*)d_ws;

    void* args[] = {(void*)&x, (void*)&A, (void*)&B, (void*)&C,
                    (void*)&Dp, (void*)&out, (void*)&ws};
    hipError_t e = hipLaunchCooperativeKernel((const void*)megak, dim3(256), dim3(512),
                                              args, 0, stream);
    if (e == hipSuccess) return;

    // ---- fallback: round-4 multi-kernel pipeline ----
    float* P2    = ws + WS_P2;
    float* P4    = ws + WS_P4;
    float* P8    = ws + WS_P8;
    float* P16   = ws + WS_P16;
    float* P32   = ws + WS_P32;
    float* P64T  = ws + WS_P64T;
    float* P128T = ws + WS_P128T;
    float* Wm    = ws + WS_W;
    float* Vm    = ws + WS_V;
    float* K     = ws + WS_K;
    short* XHs   = (short*)(ws + WS_XH);
    short* XLs   = (short*)(ws + WS_XL);
    short* AHs   = (short*)(ws + WS_AH);
    short* ALs   = (short*)(ws + WS_AL);

    xsplit<<<512, 256, 0, stream>>>(x, XHs, XLs);
    mmrow<<<256, 1024, 0, stream>>>(A, A, P2);
    mmrow<<<256, 1024, 0, stream>>>(P2, P2, P4);
    mmrow<<<256, 1024, 0, stream>>>(P4, P4, P8);
    mmrow<<<256, 1024, 0, stream>>>(P8, P8, P16);
    mmrow<<<256, 1024, 0, stream>>>(P16, P16, P32);
    mm2<<<256, 1024, 0, stream>>>(P32, P64T);
    mmrow<<<256, 1024, 0, stream>>>(P64T, P64T, P128T);
    wvgen<<<4, 1024, 0, stream>>>(A, B, C, P32, P64T, P128T, Wm, Vm);
    kdot<<<64, 256, 0, stream>>>(Wm, Vm, K);
    afrag<<<64, 256, 0, stream>>>(K, AHs, ALs);
    convm<<<256, 512, 0, stream>>>(XHs, XLs, AHs, ALs, x, Dp, out);
}

// Round 6
// 126.410 us; speedup vs baseline: 3.5048x; 3.5048x over previous
//
#include <hip/hip_runtime.h>

// ---------------------------------------------------------------------------
// HiPPO-LegT via scalar-kernel convolution (10-launch pipeline):
//   pred[b][t] = fac_t * sum_{s<=t} k[t-s] x[b][s] + D x[b][t],  k[tau]=C A^tau B
// k factorized: k[64q+r] = (C A^r) . (A^{64q} B) = W[r] . V[q]
//   W: 4 chains x 16 steps stepping A   (starts C, C P16, C P32, C P16 P32)
//   V: 2 chains x 32 steps stepping A^128 (starts B, P64 B)
// kfrag: fuses K dots + Toeplitz MFMA A-fragment build (no K round-trip).
// convm: MFMA GEMM vs Toeplitz, contiguous chunks + A-frag register rotation.
// ---------------------------------------------------------------------------

#define LENGTH 4096

// ws layout (float offsets)
#define WS_P2    0
#define WS_P4    65536
#define WS_P8    131072
#define WS_P16   196608
#define WS_P32   262144
#define WS_P64T  327680
#define WS_P128T 393216
#define WS_W     458752   // 64 x 256
#define WS_V     475136   // 64 x 256
#define WS_XH    491520   // 1M shorts = 524288 floats
#define WS_XL    1015808
#define WS_AH    1540096  // 256*64*8 shorts = 65536 floats
#define WS_AL    1605632

typedef __attribute__((ext_vector_type(8))) short bf16x8;
typedef __attribute__((ext_vector_type(4))) float f32x4;
#define MFMA(a, b, c) __builtin_amdgcn_mfma_f32_16x16x32_bf16(a, b, c, 0, 0, 0)

__device__ inline unsigned short f2bf(float f) {
    unsigned int u = __float_as_uint(f);
    return (unsigned short)((u + 0x7FFFu + ((u >> 16) & 1u)) >> 16);
}
__device__ inline void split2(float f, short& h, short& l) {
    unsigned short hu = f2bf(f);
    float fh = __uint_as_float((unsigned int)hu << 16);
    h = (short)hu;
    l = (short)f2bf(f - fh);
}

// ---- 256x256 row-matmul body: Z(row) = X(row) * Y; 1024 thr, k-split 4 ----
__device__ __forceinline__ void mm_body(const float* __restrict__ X,
                                        const float* __restrict__ Y,
                                        float* __restrict__ Z,
                                        int row, int t, bool trans, float* red) {
    const int j = t & 255, p = t >> 8;
    const float* xr = X + row * 256 + 64 * p;
    const float* yc = Y + (64 * p) * 256 + j;
    float a0 = 0.f, a1 = 0.f, a2 = 0.f, a3 = 0.f;
#pragma unroll
    for (int l = 0; l < 64; l += 4) {
        a0 = fmaf(xr[l + 0], yc[(l + 0) * 256], a0);
        a1 = fmaf(xr[l + 1], yc[(l + 1) * 256], a1);
        a2 = fmaf(xr[l + 2], yc[(l + 2) * 256], a2);
        a3 = fmaf(xr[l + 3], yc[(l + 3) * 256], a3);
    }
    float s = (a0 + a1) + (a2 + a3);
    if (p) red[(p - 1) * 256 + j] = s;
    __syncthreads();
    if (!p) {
        float z = s + red[j] + red[256 + j] + red[512 + j];
        if (trans) Z[j * 256 + row] = z;
        else       Z[row * 256 + j] = z;
    }
}

// ---- L0: blocks 0..255: P2 = A*A; blocks 256..383: xsplit (16 wave-jobs) ----
__global__ __launch_bounds__(1024) void fused0(const float* __restrict__ A,
                                               const float* __restrict__ x,
                                               float* __restrict__ P2,
                                               short* __restrict__ XH,
                                               short* __restrict__ XL) {
    __shared__ float red[3 * 256];
    const int t = threadIdx.x;
    if (blockIdx.x < 256) {
        mm_body(A, A, P2, blockIdx.x, t, false, red);
        return;
    }
    const int wv = t >> 6, lane = t & 63;
    const int pj = (blockIdx.x - 256) * 16 + wv;       // 0..2047
    const int c = pj >> 4, blk = pj & 15;
    const int b = blk * 16 + (lane & 15);
    const int s0 = c * 32 + 8 * (lane >> 4);
    const float4 v0 = reinterpret_cast<const float4*>(&x[b * LENGTH + s0])[0];
    const float4 v1 = reinterpret_cast<const float4*>(&x[b * LENGTH + s0])[1];
    const float f[8] = {v0.x, v0.y, v0.z, v0.w, v1.x, v1.y, v1.z, v1.w};
    bf16x8 hv, lv;
#pragma unroll
    for (int e = 0; e < 8; ++e) {
        short h, l;
        split2(f[e], h, l);
        hv[e] = h; lv[e] = l;
    }
    const int off = (pj * 64 + lane) * 8;
    *reinterpret_cast<bf16x8*>(XH + off) = hv;
    *reinterpret_cast<bf16x8*>(XL + off) = lv;
}

// ---- generic squaring: D = S*S (optionally transposed store) ----
__global__ __launch_bounds__(1024) void mmsq(const float* __restrict__ S,
                                             float* __restrict__ D) {
    __shared__ float red[3 * 256];
    mm_body(S, S, D, blockIdx.x, threadIdx.x, false, red);
}
__global__ __launch_bounds__(1024) void mmsqT(const float* __restrict__ S,
                                              float* __restrict__ D) {
    __shared__ float red[3 * 256];
    mm_body(S, S, D, blockIdx.x, threadIdx.x, true, red);
}

// ---- L6: blocks 0..255: P128T = P64T*P64T; blocks 256..259: W chains ----
__global__ __launch_bounds__(1024) void p128w(const float* __restrict__ P64T,
                                              float* __restrict__ P128T,
                                              const float* __restrict__ A,
                                              const float* __restrict__ C,
                                              const float* __restrict__ P16,
                                              const float* __restrict__ P32,
                                              float* __restrict__ W) {
    __shared__ float red[3 * 256];
    __shared__ float cur[256];
    __shared__ float red4[4][256];
    const int t = threadIdx.x;
    if (blockIdx.x < 256) {
        mm_body(P64T, P64T, P128T, blockIdx.x, t, false, red);
        return;
    }
    const int c = blockIdx.x - 256;              // chain 0..3
    const int j = t & 255, p = t >> 8;
    float areg[64];
#pragma unroll
    for (int ii = 0; ii < 64; ++ii) areg[ii] = A[(64 * p + ii) * 256 + j];

    // start = C * A^{16c}
    if (c == 0) {
        if (t < 256) cur[t] = C[t];
        __syncthreads();
    } else {
        const float* M1 = (c == 2) ? P32 : P16;
        float s0 = 0.f, s1 = 0.f;
#pragma unroll
        for (int ii = 0; ii < 64; ii += 2) {
            s0 = fmaf(C[64 * p + ii],     M1[(64 * p + ii) * 256 + j],     s0);
            s1 = fmaf(C[64 * p + ii + 1], M1[(64 * p + ii + 1) * 256 + j], s1);
        }
        red4[p][j] = s0 + s1;
        __syncthreads();
        if (!p) cur[j] = red4[0][j] + red4[1][j] + red4[2][j] + red4[3][j];
        __syncthreads();
        if (c == 3) {                            // * P32
            float q0 = 0.f, q1 = 0.f;
#pragma unroll
            for (int ii = 0; ii < 64; ii += 2) {
                q0 = fmaf(cur[64 * p + ii],     P32[(64 * p + ii) * 256 + j],     q0);
                q1 = fmaf(cur[64 * p + ii + 1], P32[(64 * p + ii + 1) * 256 + j], q1);
            }
            red4[p][j] = q0 + q1;
            __syncthreads();
            if (!p) cur[j] = red4[0][j] + red4[1][j] + red4[2][j] + red4[3][j];
            __syncthreads();
        }
    }
    // 16 steps stepping A
    for (int s_ = 0; s_ < 16; ++s_) {
        if (!p) W[(16 * c + s_) * 256 + j] = cur[j];
        if (s_ == 15) break;
        float s0 = 0.f, s1 = 0.f;
#pragma unroll
        for (int m = 0; m < 16; ++m) {
            float4 c4 = *reinterpret_cast<const float4*>(&cur[64 * p + 4 * m]);
            s0 = fmaf(c4.x, areg[4 * m + 0], s0);
            s1 = fmaf(c4.y, areg[4 * m + 1], s1);
            s0 = fmaf(c4.z, areg[4 * m + 2], s0);
            s1 = fmaf(c4.w, areg[4 * m + 3], s1);
        }
        red4[p][j] = s0 + s1;
        __syncthreads();
        if (!p) cur[j] = red4[0][j] + red4[1][j] + red4[2][j] + red4[3][j];
        __syncthreads();
    }
}

// ---- L7: V chains: block c in {0,1}: V[2s+c] = A^{128s} (A^{64c} B) ----
__global__ __launch_bounds__(1024) void vgen(const float* __restrict__ P64T,
                                             const float* __restrict__ P128T,
                                             const float* __restrict__ B,
                                             float* __restrict__ V) {
    __shared__ float cur[256];
    __shared__ float red4[4][256];
    const int t = threadIdx.x;
    const int i = t & 255, p = t >> 8;
    const int c = blockIdx.x;
    float mreg[64];
#pragma unroll
    for (int jj = 0; jj < 64; ++jj) mreg[jj] = P128T[(64 * p + jj) * 256 + i];

    if (c == 0) {
        if (t < 256) cur[t] = B[t];
        __syncthreads();
    } else {                                     // cur = A^64 B via P64T
        float s0 = 0.f, s1 = 0.f;
#pragma unroll
        for (int jj = 0; jj < 64; jj += 2) {
            s0 = fmaf(P64T[(64 * p + jj) * 256 + i],     B[64 * p + jj],     s0);
            s1 = fmaf(P64T[(64 * p + jj + 1) * 256 + i], B[64 * p + jj + 1], s1);
        }
        red4[p][i] = s0 + s1;
        __syncthreads();
        if (!p) cur[i] = red4[0][i] + red4[1][i] + red4[2][i] + red4[3][i];
        __syncthreads();
    }
    for (int s_ = 0; s_ < 32; ++s_) {
        if (!p) V[(2 * s_ + c) * 256 + i] = cur[i];
        if (s_ == 31) break;
        float s0 = 0.f, s1 = 0.f;
#pragma unroll
        for (int m = 0; m < 16; ++m) {
            float4 c4 = *reinterpret_cast<const float4*>(&cur[64 * p + 4 * m]);
            s0 = fmaf(c4.x, mreg[4 * m + 0], s0);
            s1 = fmaf(c4.y, mreg[4 * m + 1], s1);
            s0 = fmaf(c4.z, mreg[4 * m + 2], s0);
            s1 = fmaf(c4.w, mreg[4 * m + 3], s1);
        }
        red4[p][i] = s0 + s1;
        __syncthreads();
        if (!p) cur[i] = red4[0][i] + red4[1][i] + red4[2][i] + red4[3][i];
        __syncthreads();
    }
}

// ---- L8: kfrag: block b computes k[128b-15 .. 128b+127] dots and builds
//      A-frag entries m = 8b..8b+7 (fused kdot+afrag, no K round-trip) ----
__global__ __launch_bounds__(256) void kfrag(const float* __restrict__ Wm,
                                             const float* __restrict__ Vm,
                                             short* __restrict__ AH,
                                             short* __restrict__ AL) {
    const int bid = blockIdx.x, t = threadIdx.x;
    __shared__ float Wl[64 * 257];
    __shared__ float Vl[3 * 256];
    __shared__ float kl[144];
    for (int r = 0; r < 64; ++r) Wl[r * 257 + t] = Wm[r * 256 + t];
#pragma unroll
    for (int qq = 0; qq < 3; ++qq) {
        const int q = 2 * bid - 1 + qq;
        Vl[qq * 256 + t] = (q >= 0) ? Vm[q * 256 + t] : 0.f;
    }
    __syncthreads();
    if (t < 143) {
        const int tau = 128 * bid - 15 + t;
        float s = 0.f;
        if (tau >= 0) {
            const int r = tau & 63;
            const int qq = (tau >> 6) - (2 * bid - 1);
            const float* wr = &Wl[r * 257];
            const float* vr = &Vl[qq * 256];
            float s0 = 0.f, s1 = 0.f, s2 = 0.f, s3 = 0.f;
#pragma unroll 16
            for (int i = 0; i < 256; i += 4) {
                s0 = fmaf(wr[i + 0], vr[i + 0], s0);
                s1 = fmaf(wr[i + 1], vr[i + 1], s1);
                s2 = fmaf(wr[i + 2], vr[i + 2], s2);
                s3 = fmaf(wr[i + 3], vr[i + 3], s3);
            }
            s = (s0 + s1) + (s2 + s3);
        }
        kl[t] = s;
    }
    __syncthreads();
    const int wv = t >> 6, lane = t & 63;
#pragma unroll
    for (int e2 = 0; e2 < 2; ++e2) {
        const int ep = 2 * wv + e2;               // 0..7
        const int m = 8 * bid + ep;
        bf16x8 hv, lv;
#pragma unroll
        for (int el = 0; el < 8; ++el) {
            const int rel = 16 * ep + (lane & 15) - 8 * (lane >> 4) - el + 15;
            short h, l;
            split2(kl[rel], h, l);
            hv[el] = h; lv[el] = l;
        }
        const int off = (m * 64 + lane) * 8;
        *reinterpret_cast<bf16x8*>(AH + off) = hv;
        *reinterpret_cast<bf16x8*>(AL + off) = lv;
    }
}

// ---- L9: MFMA conv: 256 blocks = 32 pairs x 8 btiles(32b); 8 waves take
// contiguous chunk ranges of the pair's 130 chunks; A-frag register rotation;
// LDS reduce; coalesced exclusive float4 stores. ----
#define AHP(M_) (*reinterpret_cast<const bf16x8*>(AH + ((M_) * 64 + lane) * 8))
#define ALP(M_) (*reinterpret_cast<const bf16x8*>(AL + ((M_) * 64 + lane) * 8))
#define XHP(O_) (*reinterpret_cast<const bf16x8*>(XH + (O_)))
#define XLP(O_) (*reinterpret_cast<const bf16x8*>(XL + (O_)))

#define ONER6(AHF, ALF, T, R)                                   \
    acc[T][R][0] = MFMA(AHF, bh0, acc[T][R][0]);                \
    acc[T][R][1] = MFMA(AHF, bh1, acc[T][R][1]);                \
    acc[T][R][0] = MFMA(AHF, bl0, acc[T][R][0]);                \
    acc[T][R][1] = MFMA(AHF, bl1, acc[T][R][1]);                \
    acc[T][R][0] = MFMA(ALF, bh0, acc[T][R][0]);                \
    acc[T][R][1] = MFMA(ALF, bh1, acc[T][R][1]);

#define APPLYT(T)                                               \
    { if (d >= 0)      { ONER6(ah0, al0, T, 0) }                \
      if (d + 16 >= 0) { ONER6(ah1, al1, T, 1) }                \
      if (d + 32 >= 0) { ONER6(ah2, al2, T, 2) }                \
      if (d + 48 >= 0) { ONER6(ah3, al3, T, 3) } }

#define LOADA_FULL(D_)                                          \
    { const int m0_ = ((D_) > 0 ? (D_) : 0) >> 4;               \
      const int m1_ = ((D_) + 16 > 0 ? (D_) + 16 : 0) >> 4;     \
      const int m2_ = ((D_) + 32 > 0 ? (D_) + 32 : 0) >> 4;     \
      const int m3_ = ((D_) + 48 > 0 ? (D_) + 48 : 0) >> 4;     \
      ah0 = AHP(m0_); al0 = ALP(m0_);                           \
      ah1 = AHP(m1_); al1 = ALP(m1_);                           \
      ah2 = AHP(m2_); al2 = ALP(m2_);                           \
      ah3 = AHP(m3_); al3 = ALP(m3_); }

__global__ __launch_bounds__(512) void convm(const short* __restrict__ XH,
                                             const short* __restrict__ XL,
                                             const short* __restrict__ AH,
                                             const short* __restrict__ AL,
                                             const float* __restrict__ x,
                                             const float* __restrict__ Dp,
                                             float* __restrict__ out) {
    const int pr = blockIdx.x & 31;
    const int bt = blockIdx.x >> 5;
    const int tid = threadIdx.x;
    const int w = tid >> 6, lane = tid & 63;
    const int tA64 = pr * 64, tB64 = (63 - pr) * 64;
    const int nA = 2 * pr + 2;
    const int bt2 = bt * 2;
    __shared__ float lds[16 * 64 * 34];

    f32x4 acc[2][4][2];
#pragma unroll
    for (int t_ = 0; t_ < 2; ++t_)
#pragma unroll
        for (int r_ = 0; r_ < 4; ++r_)
#pragma unroll
            for (int c_ = 0; c_ < 2; ++c_) acc[t_][r_][c_] = f32x4{0.f, 0.f, 0.f, 0.f};

    const int lo = (130 * w) >> 3, hi = (130 * (w + 1)) >> 3;

    bf16x8 ah0, ah1, ah2, ah3, al0, al1, al2, al3, bh0, bh1, bl0, bl1;
    int idx = lo;
    int tile = (idx < nA) ? 0 : 1;
    int cc = idx - (tile ? nA : 0);
    int d = (tile ? tB64 : tA64) - 32 * cc;
    LOADA_FULL(d);
    {
        const int xo = ((cc * 16 + bt2) * 64 + lane) * 8;
        bh0 = XHP(xo); bh1 = XHP(xo + 512);
        bl0 = XLP(xo); bl1 = XLP(xo + 512);
    }

    while (true) {
        const int nxt = idx + 1;
        const bool hn = nxt < hi;
        bf16x8 tbh0, tbh1, tbl0, tbl1, tah0, tah1, tal0, tal1;
        int tilen = tile, dn = d;
        bool sw = false;
        if (hn) {
            tilen = (nxt < nA) ? 0 : 1;
            const int ccn = nxt - (tilen ? nA : 0);
            dn = (tilen ? tB64 : tA64) - 32 * ccn;
            sw = (tilen != tile);
            const int xo = ((ccn * 16 + bt2) * 64 + lane) * 8;
            tbh0 = XHP(xo); tbh1 = XHP(xo + 512);
            tbl0 = XLP(xo); tbl1 = XLP(xo + 512);
            if (!sw) {
                const int n0 = (dn > 0 ? dn : 0) >> 4;
                const int n1 = (dn + 16 > 0 ? dn + 16 : 0) >> 4;
                tah0 = AHP(n0); tal0 = ALP(n0);
                tah1 = AHP(n1); tal1 = ALP(n1);
            }
        }
        if (tile == 0) { APPLYT(0) } else { APPLYT(1) }
        if (!hn) break;
        if (!sw) {
            ah3 = ah1; ah2 = ah0; al3 = al1; al2 = al0;
            ah0 = tah0; ah1 = tah1; al0 = tal0; al1 = tal1;
        } else {
            LOADA_FULL(dn);
        }
        bh0 = tbh0; bh1 = tbh1; bl0 = tbl0; bl1 = tbl1;
        tile = tilen; d = dn; idx = nxt;
    }

    // flush per-wave partials to LDS
    const int lq = lane >> 4, lr = lane & 15;
#pragma unroll
    for (int t_ = 0; t_ < 2; ++t_)
#pragma unroll
        for (int r_ = 0; r_ < 4; ++r_)
#pragma unroll
            for (int c_ = 0; c_ < 2; ++c_)
#pragma unroll
                for (int e_ = 0; e_ < 4; ++e_)
                    lds[((w * 2 + t_) * 64 + (r_ * 16 + lq * 4 + e_)) * 34 +
                        (c_ * 16 + lr)] = acc[t_][r_][c_][e_];
    __syncthreads();

    // reduce 8 waves + fold D*x + t0 fix; coalesced float4 stores
    const float D = Dp[0];
    const int b = tid >> 4;
    const int t4 = (tid & 15) * 4;
#pragma unroll
    for (int t_ = 0; t_ < 2; ++t_) {
        const int tbase = t_ ? tB64 : tA64;
        float s0 = 0.f, s1 = 0.f, s2 = 0.f, s3 = 0.f;
#pragma unroll
        for (int w_ = 0; w_ < 8; ++w_) {
            const float* lp = &lds[((w_ * 2 + t_) * 64 + t4) * 34 + b];
            s0 += lp[0]; s1 += lp[34]; s2 += lp[68]; s3 += lp[102];
        }
        const int g = (bt * 32 + b) * LENGTH + tbase + t4;
        const float4 xv = *reinterpret_cast<const float4*>(x + g);
        float4 o;
        o.x = 2.f * s0 + D * xv.x;
        o.y = 2.f * s1 + D * xv.y;
        o.z = 2.f * s2 + D * xv.z;
        o.w = 2.f * s3 + D * xv.w;
        if (tbase == 0 && t4 == 0) o.x -= s0;     // t==0: fac is 1, not 2
        *reinterpret_cast<float4*>(out + g) = o;
    }
}

extern "C" void kernel_launch(void* const* d_in, const int* in_sizes, int n_in,
                              void* d_out, int out_size, void* d_ws, size_t ws_size,
                              hipStream_t stream) {
    const float* x  = (const float*)d_in[0];
    const float* A  = (const float*)d_in[1];
    const float* B  = (const float*)d_in[2];
    const float* C  = (const float*)d_in[3];
    const float* Dp = (const float*)d_in[4];
    float* out = (float*)d_out;
    float* ws  = (float*)d_ws;

    float* P2    = ws + WS_P2;
    float* P4    = ws + WS_P4;
    float* P8    = ws + WS_P8;
    float* P16   = ws + WS_P16;
    float* P32   = ws + WS_P32;
    float* P64T  = ws + WS_P64T;
    float* P128T = ws + WS_P128T;
    float* Wm    = ws + WS_W;
    float* Vm    = ws + WS_V;
    short* XHs   = (short*)(ws + WS_XH);
    short* XLs   = (short*)(ws + WS_XL);
    short* AHs   = (short*)(ws + WS_AH);
    short* ALs   = (short*)(ws + WS_AL);

    fused0<<<384, 1024, 0, stream>>>(A, x, P2, XHs, XLs);
    mmsq<<<256, 1024, 0, stream>>>(P2, P4);
    mmsq<<<256, 1024, 0, stream>>>(P4, P8);
    mmsq<<<256, 1024, 0, stream>>>(P8, P16);
    mmsq<<<256, 1024, 0, stream>>>(P16, P32);
    mmsqT<<<256, 1024, 0, stream>>>(P32, P64T);
    p128w<<<260, 1024, 0, stream>>>(P64T, P128T, A, C, P16, P32, Wm);
    vgen<<<2, 1024, 0, stream>>>(P64T, P128T, B, Vm);
    kfrag<<<32, 256, 0, stream>>>(Wm, Vm, AHs, ALs);
    convm<<<256, 512, 0, stream>>>(XHs, XLs, AHs, ALs, x, Dp, out);
}